// Round 4
// baseline (1515.370 us; speedup 1.0000x reference)
//
#include <hip/hip_runtime.h>
#include <hip/hip_bf16.h>
#include <hip/hip_fp16.h>

// LieMoE: tokens, in_dim, hidden, out_dim, experts, topk
#define N_TOK 8192
#define DIM_D 1024
#define DIM_H 4096
#define DIM_O 1024
#define NEXP  8
#define TOPK  3

// Sparse routing capacity: sum of per-expert counts == N_TOK*TOPK = 24576.
// 256-aligned per-expert padding adds < 8*256 -> 26624 rows, <= 104 m-tiles.
#define CAP_ROWS  26624
#define MAX_TILES 104
#define NXCD      8
#define NMT_XCD   (MAX_TILES / NXCD)   // 13 m-tiles per XCD chunk

typedef _Float16 f16_t;
typedef _Float16 f16x4 __attribute__((ext_vector_type(4)));
typedef _Float16 f16x8 __attribute__((ext_vector_type(8)));
typedef float    floatx4 __attribute__((ext_vector_type(4)));

__device__ __forceinline__ void gld_lds16(const void* g, void* l) {
  __builtin_amdgcn_global_load_lds(
      (__attribute__((address_space(1))) void*)(void*)g,
      (__attribute__((address_space(3))) void*)l, 16, 0, 0);
}

// XCD-chunked decode: xcd = bid%8 owns contiguous m-tile chunk (=> ~one
// expert's B panel per XCD L2); within chunk, n varies fastest so consecutive
// blocks on an XCD share the A-tile. (Proven R1 lever: FETCH 957->215 MB.)
__device__ __forceinline__ void decode_tile(int bid, int nbn, int* mt, int* nidx) {
  const int xcd = bid & (NXCD - 1);
  const int lid = bid >> 3;
  const int m_local = lid / nbn;
  *nidx = lid - m_local * nbn;
  *mt = xcd * NMT_XCD + m_local;
}

// ---------------------------------------------------------------------------
// Gate: fp32 scores, softmax, top-3 (stable, first-index wins ties),
// renormalize. Also builds per-expert token lists via atomicAdd.
// One wave per token.
// ---------------------------------------------------------------------------
__global__ __launch_bounds__(256) void gate_kernel(
    const float* __restrict__ x, const float* __restrict__ gw,
    const float* __restrict__ gb, float* __restrict__ wts,
    int* __restrict__ lists, int* __restrict__ cnt) {
  const int token = blockIdx.x * 4 + (threadIdx.x >> 6);
  const int lane = threadIdx.x & 63;
  float s[NEXP];
#pragma unroll
  for (int e = 0; e < NEXP; e++) s[e] = 0.f;
  const float* xr = x + (size_t)token * DIM_D;
  for (int d = lane; d < DIM_D; d += 64) {
    const float xv = xr[d];
    const float* g = gw + (size_t)d * NEXP;
#pragma unroll
    for (int e = 0; e < NEXP; e++) s[e] += xv * g[e];
  }
#pragma unroll
  for (int off = 32; off > 0; off >>= 1) {
#pragma unroll
    for (int e = 0; e < NEXP; e++) s[e] += __shfl_xor(s[e], off, 64);
  }
#pragma unroll
  for (int e = 0; e < NEXP; e++) s[e] += gb[e];

  float mx = s[0];
#pragma unroll
  for (int e = 1; e < NEXP; e++) mx = fmaxf(mx, s[e]);
  float p[NEXP];
  float den = 0.f;
#pragma unroll
  for (int e = 0; e < NEXP; e++) { p[e] = expf(s[e] - mx); den += p[e]; }

  bool sel[NEXP];
#pragma unroll
  for (int e = 0; e < NEXP; e++) sel[e] = false;
  for (int k = 0; k < TOPK; k++) {
    int bj = 0;
    float bv = -1e30f;
#pragma unroll
    for (int e = 0; e < NEXP; e++) {
      if (!sel[e] && s[e] > bv) { bv = s[e]; bj = e; }
    }
    sel[bj] = true;
  }
  float msum = 1e-8f * den;
#pragma unroll
  for (int e = 0; e < NEXP; e++) msum += sel[e] ? p[e] : 0.f;
  const float inv = 1.f / msum;
  if (lane < NEXP) {
    wts[(size_t)token * NEXP + lane] = sel[lane] ? p[lane] * inv : 0.f;
  }
  if (lane == 0) {
#pragma unroll
    for (int e = 0; e < NEXP; e++) {
      if (sel[e]) {
        const int pos = atomicAdd(&cnt[e], 1);
        lists[e * N_TOK + pos] = token;
      }
    }
  }
}

// ---------------------------------------------------------------------------
// Plan: 256-aligned prefix sums of counts -> start rows; flat m-tile table.
// Entry: (expert << 16) | (tile_row0 >> 8)
// ---------------------------------------------------------------------------
__global__ void plan_kernel(const int* __restrict__ cnt, int* __restrict__ start,
                            int* __restrict__ table, int* __restrict__ total) {
  if (threadIdx.x == 0) {
    int r0 = 0, t = 0;
    for (int e = 0; e < NEXP; e++) {
      start[e] = r0;
      const int nt = (cnt[e] + 255) >> 8;
      for (int i = 0; i < nt; i++) table[t++] = (e << 16) | ((r0 >> 8) + i);
      r0 += nt << 8;
    }
    total[0] = t;
  }
}

// ---------------------------------------------------------------------------
// Fill compact-row metadata: rowtok (token index or -1 for pad), roww (weight)
// ---------------------------------------------------------------------------
__global__ __launch_bounds__(256) void fill_kernel(
    const int* __restrict__ cnt, const int* __restrict__ start,
    const int* __restrict__ lists, const float* __restrict__ wts,
    int* __restrict__ rowtok, float* __restrict__ roww) {
  const int e = blockIdx.y;
  const int i = blockIdx.x * 256 + threadIdx.x;
  const int c = cnt[e];
  const int pad = (c + 255) & ~255;
  if (i >= pad) return;
  const int r = start[e] + i;
  if (i < c) {
    const int t = lists[e * N_TOK + i];
    rowtok[r] = t;
    roww[r] = wts[(size_t)t * NEXP + e];
  } else {
    rowtok[r] = -1;
    roww[r] = 0.f;
  }
}

// ---------------------------------------------------------------------------
// fp32 -> f16 elementwise (x)
// ---------------------------------------------------------------------------
__global__ __launch_bounds__(256) void cvt_f32_f16(
    const float* __restrict__ in, f16_t* __restrict__ out, int n4) {
  const int i = blockIdx.x * 256 + threadIdx.x;
  if (i >= n4) return;
  const float4 v = ((const float4*)in)[i];
  f16x4 o;
  o.x = (f16_t)v.x; o.y = (f16_t)v.y; o.z = (f16_t)v.z; o.w = (f16_t)v.w;
  ((f16x4*)out)[i] = o;
}

// ---------------------------------------------------------------------------
// fp32 [E][R][C] -> f16 [E][C][R] tiled transpose-convert (32x32 via LDS)
// ---------------------------------------------------------------------------
__global__ __launch_bounds__(256) void cvt_transpose(
    const float* __restrict__ in, f16_t* __restrict__ out, int R, int C) {
  __shared__ float tile[32][33];
  const int e = blockIdx.z;
  const int r0 = blockIdx.y * 32, c0 = blockIdx.x * 32;
  const int lc = threadIdx.x & 31, lr0 = threadIdx.x >> 5;
  const float* src = in + (size_t)e * R * C;
#pragma unroll
  for (int i = 0; i < 4; i++) {
    const int rr = lr0 + i * 8;
    tile[rr][lc] = src[(size_t)(r0 + rr) * C + c0 + lc];
  }
  __syncthreads();
  f16_t* dst = out + (size_t)e * C * R;
#pragma unroll
  for (int i = 0; i < 4; i++) {
    const int cc = lr0 + i * 8;
    dst[(size_t)(c0 + cc) * R + r0 + lc] = (f16_t)tile[lc][cc];
  }
}

// ===========================================================================
// 256x256 tile, BK=64, 512 threads (8 waves, 2M x 4N), per-wave out 128x64,
// double-buffered LDS (128 KB), ONE __syncthreads per K-tile (2-phase):
//   STAGE(buf^1, t+1) issued right after the barrier, so its L3 latency hides
//   under this K-tile's ds_read+MFMA; the next barrier's implicit vmcnt(0)
//   drains it. Linear LDS [row][64] (T2 measured-null at 2-phase).
// 2x arithmetic intensity vs 128^2: halves staging traffic -> attacks the
// per-XCD L2 capacity-miss that made gemm2 L3-latency-bound.
// ===========================================================================

// ---------------------------------------------------------------------------
// Merged sparse GEMM1: hg[r, 0..Hc) = relu( x[rowtok[r]] @ W1[e][:, cH+*] + b1 )
// ---------------------------------------------------------------------------
__global__ __launch_bounds__(512, 2) void gemm1_moe(
    const f16_t* __restrict__ xb, const f16_t* __restrict__ w1t,
    const float* __restrict__ b1, const int* __restrict__ rowtok,
    const int* __restrict__ table, const int* __restrict__ total,
    f16_t* __restrict__ hg, int Hc, int cH, int nbn) {
  int mt, nidx;
  decode_tile(blockIdx.x, nbn, &mt, &nidx);
  if (mt >= total[0]) return;
  const int ent = table[mt];
  const int e = ent >> 16;
  const int r0 = (ent & 0xffff) << 8;
  const int n0 = nidx * 256;  // within chunk

  __shared__ __align__(16) f16_t Asm[2][256 * 64];
  __shared__ __align__(16) f16_t Bsm[2][256 * 64];
  const int tid = threadIdx.x;
  const int wave = tid >> 6, lane = tid & 63;
  const int q = lane >> 4, r = lane & 15;
  const int wr = wave >> 2, wc = wave & 3;       // 2M x 4N wave grid
  const int wrM = wr * 128, wcN = wc * 64;

  const floatx4 zero = {0.f, 0.f, 0.f, 0.f};
  floatx4 acc[8][4];
#pragma unroll
  for (int mi = 0; mi < 8; mi++)
#pragma unroll
    for (int ni = 0; ni < 4; ni++) acc[mi][ni] = zero;

  const f16_t* BT = w1t + (size_t)e * DIM_H * DIM_D + (size_t)cH * DIM_D;

  // staging: 4 rounds x 512 threads x 16B cover 256 rows x 64 k (32 KB) per mat
  // round j, thread: row = j*64 + wave*8 + (lane>>3), slot = lane&7
  const int slot = lane & 7;
  const f16_t* aptr[4];
  const f16_t* bptr[4];
#pragma unroll
  for (int j = 0; j < 4; j++) {
    const int row = j * 64 + wave * 8 + (lane >> 3);
    const int tok = max(rowtok[r0 + row], 0);
    aptr[j] = xb + (size_t)tok * DIM_D + slot * 8;
    bptr[j] = BT + (size_t)(n0 + row) * DIM_D + slot * 8;
  }
  // LDS dest (wave-uniform base; HW adds lane*16)
#define STAGE1(b, kt)                                               \
  do {                                                              \
    _Pragma("unroll")                                               \
    for (int j = 0; j < 4; j++) {                                   \
      gld_lds16(aptr[j] + (kt) * 64, &Asm[b][j * 4096 + wave * 512]); \
      gld_lds16(bptr[j] + (kt) * 64, &Bsm[b][j * 4096 + wave * 512]); \
    }                                                               \
  } while (0)

  const int nk = DIM_D / 64;  // 16 K-tiles
  STAGE1(0, 0);
  int buf = 0;
  for (int t = 0; t < nk; ++t) {
    __syncthreads();  // vmcnt(0): buf's stage landed; prev reads of buf^1 done
    if (t + 1 < nk) STAGE1(buf ^ 1, t + 1);
#pragma unroll
    for (int kk = 0; kk < 2; kk++) {
      f16x8 af[8], bf[4];
#pragma unroll
      for (int mi = 0; mi < 8; mi++)
        af[mi] = *(const f16x8*)&Asm[buf][(wrM + mi * 16 + r) * 64 + kk * 32 + q * 8];
#pragma unroll
      for (int ni = 0; ni < 4; ni++)
        bf[ni] = *(const f16x8*)&Bsm[buf][(wcN + ni * 16 + r) * 64 + kk * 32 + q * 8];
#pragma unroll
      for (int mi = 0; mi < 8; mi++)
#pragma unroll
        for (int ni = 0; ni < 4; ni++)
          acc[mi][ni] = __builtin_amdgcn_mfma_f32_16x16x32_f16(
              af[mi], bf[ni], acc[mi][ni], 0, 0, 0);
    }
    buf ^= 1;
  }
#undef STAGE1

  // D-layout: col = lane&15, row = (lane>>4)*4 + reg
#pragma unroll
  for (int mi = 0; mi < 8; mi++)
#pragma unroll
    for (int ni = 0; ni < 4; ni++) {
      const int gcol = n0 + wcN + ni * 16 + r;
      const float bv = b1[(size_t)e * DIM_H + cH + gcol];
#pragma unroll
      for (int rr = 0; rr < 4; rr++) {
        const int grow = r0 + wrM + mi * 16 + q * 4 + rr;
        hg[(size_t)grow * Hc + gcol] = (f16_t)fmaxf(acc[mi][ni][rr] + bv, 0.f);
      }
    }
}

// ---------------------------------------------------------------------------
// Merged sparse GEMM2: out[rowtok[r]] += roww[r] * ( hg[r] @ W2[e][cH.., :] + b2 )
// Scatter via unsafeAtomicAdd (native global_atomic_add_f32).
// ---------------------------------------------------------------------------
__global__ __launch_bounds__(512, 2) void gemm2_moe(
    const f16_t* __restrict__ hg, const f16_t* __restrict__ w2t,
    const float* __restrict__ b2, const int* __restrict__ rowtok,
    const float* __restrict__ roww, const int* __restrict__ table,
    const int* __restrict__ total, float* __restrict__ out, int Hc, int cH,
    int addBias) {
  int mt, nidx;
  decode_tile(blockIdx.x, DIM_O / 256, &mt, &nidx);
  if (mt >= total[0]) return;
  const int ent = table[mt];
  const int e = ent >> 16;
  const int r0 = (ent & 0xffff) << 8;
  const int n0 = nidx * 256;  // O cols

  __shared__ __align__(16) f16_t Asm[2][256 * 64];
  __shared__ __align__(16) f16_t Bsm[2][256 * 64];
  const int tid = threadIdx.x;
  const int wave = tid >> 6, lane = tid & 63;
  const int q = lane >> 4, r = lane & 15;
  const int wr = wave >> 2, wc = wave & 3;
  const int wrM = wr * 128, wcN = wc * 64;

  const floatx4 zero = {0.f, 0.f, 0.f, 0.f};
  floatx4 acc[8][4];
#pragma unroll
  for (int mi = 0; mi < 8; mi++)
#pragma unroll
    for (int ni = 0; ni < 4; ni++) acc[mi][ni] = zero;

  const f16_t* BT = w2t + (size_t)e * DIM_O * DIM_H + cH;

  const int slot = lane & 7;
  const f16_t* aptr[4];
  const f16_t* bptr[4];
#pragma unroll
  for (int j = 0; j < 4; j++) {
    const int row = j * 64 + wave * 8 + (lane >> 3);
    aptr[j] = hg + (size_t)(r0 + row) * Hc + slot * 8;
    bptr[j] = BT + (size_t)(n0 + row) * DIM_H + slot * 8;
  }
#define STAGE2(b, kt)                                               \
  do {                                                              \
    _Pragma("unroll")                                               \
    for (int j = 0; j < 4; j++) {                                   \
      gld_lds16(aptr[j] + (kt) * 64, &Asm[b][j * 4096 + wave * 512]); \
      gld_lds16(bptr[j] + (kt) * 64, &Bsm[b][j * 4096 + wave * 512]); \
    }                                                               \
  } while (0)

  const int nk = Hc / 64;  // 32 K-tiles at Hc=2048
  STAGE2(0, 0);
  int buf = 0;
  for (int t = 0; t < nk; ++t) {
    __syncthreads();
    if (t + 1 < nk) STAGE2(buf ^ 1, t + 1);
#pragma unroll
    for (int kk = 0; kk < 2; kk++) {
      f16x8 af[8], bf[4];
#pragma unroll
      for (int mi = 0; mi < 8; mi++)
        af[mi] = *(const f16x8*)&Asm[buf][(wrM + mi * 16 + r) * 64 + kk * 32 + q * 8];
#pragma unroll
      for (int ni = 0; ni < 4; ni++)
        bf[ni] = *(const f16x8*)&Bsm[buf][(wcN + ni * 16 + r) * 64 + kk * 32 + q * 8];
#pragma unroll
      for (int mi = 0; mi < 8; mi++)
#pragma unroll
        for (int ni = 0; ni < 4; ni++)
          acc[mi][ni] = __builtin_amdgcn_mfma_f32_16x16x32_f16(
              af[mi], bf[ni], acc[mi][ni], 0, 0, 0);
    }
    buf ^= 1;
  }
#undef STAGE2

#pragma unroll
  for (int mi = 0; mi < 8; mi++)
#pragma unroll
    for (int ni = 0; ni < 4; ni++) {
      const int gcol = n0 + wcN + ni * 16 + r;
      const float bv = addBias ? b2[(size_t)e * DIM_O + gcol] : 0.f;
#pragma unroll
      for (int rr = 0; rr < 4; rr++) {
        const int grow = r0 + wrM + mi * 16 + q * 4 + rr;
        const int t = rowtok[grow];
        if (t >= 0) {
          const float w = roww[grow];
          unsafeAtomicAdd(&out[(size_t)t * DIM_O + gcol],
                          w * (acc[mi][ni][rr] + bv));
        }
      }
    }
}

// ---------------------------------------------------------------------------
// launch
// ---------------------------------------------------------------------------
extern "C" void kernel_launch(void* const* d_in, const int* in_sizes, int n_in,
                              void* d_out, int out_size, void* d_ws, size_t ws_size,
                              hipStream_t stream) {
  const float* x      = (const float*)d_in[0];
  const float* gate_w = (const float*)d_in[1];
  const float* gate_b = (const float*)d_in[2];
  const float* w1     = (const float*)d_in[3];
  const float* b1     = (const float*)d_in[4];
  const float* w2     = (const float*)d_in[5];
  const float* b2     = (const float*)d_in[6];
  float* out = (float*)d_out;

  // workspace layout
  char* ws = (char*)d_ws;
  const size_t off_wts    = 0;                        // 256 KB
  const size_t off_lists  = off_wts + 262144;         // 256 KB
  const size_t off_cnt    = off_lists + 262144;       // 512 B
  const size_t off_start  = off_cnt + 512;            // 512 B
  const size_t off_total  = off_start + 512;          // 512 B
  const size_t off_table  = off_total + 512;          // 2 KB
  const size_t off_rowtok = off_table + 2048;         // 112 KB (26624*4)
  const size_t off_roww   = off_rowtok + 114688;      // 112 KB
  const size_t META       = 1 << 20;                  // 1 MB reserved
  const size_t off_w1t = META;                                        // 64 MB
  const size_t off_w2t = off_w1t + (size_t)NEXP * DIM_H * DIM_D * 2;  // 64 MB
  const size_t off_xb  = off_w2t + (size_t)NEXP * DIM_O * DIM_H * 2;  // 16 MB
  const size_t off_hg  = off_xb + (size_t)N_TOK * DIM_D * 2;

  float* wts   = (float*)(ws + off_wts);
  int*   lists = (int*)(ws + off_lists);
  int*   cnt   = (int*)(ws + off_cnt);
  int*   start = (int*)(ws + off_start);
  int*   total = (int*)(ws + off_total);
  int*   table = (int*)(ws + off_table);
  int*   rowtok= (int*)(ws + off_rowtok);
  float* roww  = (float*)(ws + off_roww);
  f16_t* w1t   = (f16_t*)(ws + off_w1t);
  f16_t* w2t   = (f16_t*)(ws + off_w2t);
  f16_t* xb    = (f16_t*)(ws + off_xb);
  f16_t* hg    = (f16_t*)(ws + off_hg);

  // pick largest H-chunk that fits (ws_size constant across calls)
  int Hc = 512;
  for (int cand = 4096; cand >= 512; cand >>= 1) {
    if (off_hg + (size_t)CAP_ROWS * cand * 2 <= ws_size) { Hc = cand; break; }
  }
  const int nchunks = DIM_H / Hc;

  hipMemsetAsync(cnt, 0, 512, stream);
  hipMemsetAsync(d_out, 0, (size_t)out_size * sizeof(float), stream);

  gate_kernel<<<N_TOK / 4, 256, 0, stream>>>(x, gate_w, gate_b, wts, lists, cnt);
  plan_kernel<<<1, 64, 0, stream>>>(cnt, start, table, total);
  fill_kernel<<<dim3(N_TOK / 256, NEXP), 256, 0, stream>>>(
      cnt, start, lists, wts, rowtok, roww);

  const int n4 = N_TOK * DIM_D / 4;
  cvt_f32_f16<<<(n4 + 255) / 256, 256, 0, stream>>>(x, xb, n4);
  cvt_transpose<<<dim3(DIM_H / 32, DIM_D / 32, NEXP), 256, 0, stream>>>(
      w1, w1t, DIM_D, DIM_H);
  cvt_transpose<<<dim3(DIM_O / 32, DIM_H / 32, NEXP), 256, 0, stream>>>(
      w2, w2t, DIM_H, DIM_O);

  for (int c = 0; c < nchunks; c++) {
    const int cH = c * Hc;
    const int nbn1 = Hc / 256;
    gemm1_moe<<<dim3(MAX_TILES * nbn1), 512, 0, stream>>>(
        xb, w1t, b1, rowtok, table, total, hg, Hc, cH, nbn1);
    gemm2_moe<<<dim3(MAX_TILES * (DIM_O / 256)), 512, 0, stream>>>(
        hg, w2t, b2, rowtok, roww, table, total, out, Hc, cH, c == 0);
  }
}

// Round 5
// 1386.460 us; speedup vs baseline: 1.0930x; 1.0930x over previous
//
#include <hip/hip_runtime.h>
#include <hip/hip_bf16.h>
#include <hip/hip_fp16.h>

// LieMoE: tokens, in_dim, hidden, out_dim, experts, topk
#define N_TOK 8192
#define DIM_D 1024
#define DIM_H 4096
#define DIM_O 1024
#define NEXP  8
#define TOPK  3

// Sparse routing capacity: sum of per-expert counts == N_TOK*TOPK = 24576.
// 256-aligned per-expert padding adds < 8*256 -> 26624 rows, <= 104 m-tiles.
#define CAP_ROWS  26624
#define MAX_TILES 104
#define NXCD      8
#define NMT_XCD   (MAX_TILES / NXCD)   // 13 m-tiles per XCD chunk

typedef _Float16 f16_t;
typedef _Float16 f16x4 __attribute__((ext_vector_type(4)));
typedef _Float16 f16x8 __attribute__((ext_vector_type(8)));
typedef float    floatx4 __attribute__((ext_vector_type(4)));

__device__ __forceinline__ void gld_lds16(const void* g, void* l) {
  __builtin_amdgcn_global_load_lds(
      (__attribute__((address_space(1))) void*)(void*)g,
      (__attribute__((address_space(3))) void*)l, 16, 0, 0);
}

// XCD-chunked decode: xcd = bid%8 owns contiguous m-tile chunk (=> ~one
// expert's B panel per XCD L2); within chunk, n varies fastest so consecutive
// blocks on an XCD share the A-tile. (Proven R1 lever: FETCH 957->215 MB.)
__device__ __forceinline__ void decode_tile(int bid, int nbn, int* mt, int* nidx) {
  const int xcd = bid & (NXCD - 1);
  const int lid = bid >> 3;
  const int m_local = lid / nbn;
  *nidx = lid - m_local * nbn;
  *mt = xcd * NMT_XCD + m_local;
}

// ---------------------------------------------------------------------------
// Gate: fp32 scores, softmax, top-3 (stable, first-index wins ties),
// renormalize. Also builds per-expert token lists via atomicAdd.
// One wave per token.
// ---------------------------------------------------------------------------
__global__ __launch_bounds__(256) void gate_kernel(
    const float* __restrict__ x, const float* __restrict__ gw,
    const float* __restrict__ gb, float* __restrict__ wts,
    int* __restrict__ lists, int* __restrict__ cnt) {
  const int token = blockIdx.x * 4 + (threadIdx.x >> 6);
  const int lane = threadIdx.x & 63;
  float s[NEXP];
#pragma unroll
  for (int e = 0; e < NEXP; e++) s[e] = 0.f;
  const float* xr = x + (size_t)token * DIM_D;
  for (int d = lane; d < DIM_D; d += 64) {
    const float xv = xr[d];
    const float* g = gw + (size_t)d * NEXP;
#pragma unroll
    for (int e = 0; e < NEXP; e++) s[e] += xv * g[e];
  }
#pragma unroll
  for (int off = 32; off > 0; off >>= 1) {
#pragma unroll
    for (int e = 0; e < NEXP; e++) s[e] += __shfl_xor(s[e], off, 64);
  }
#pragma unroll
  for (int e = 0; e < NEXP; e++) s[e] += gb[e];

  float mx = s[0];
#pragma unroll
  for (int e = 1; e < NEXP; e++) mx = fmaxf(mx, s[e]);
  float p[NEXP];
  float den = 0.f;
#pragma unroll
  for (int e = 0; e < NEXP; e++) { p[e] = expf(s[e] - mx); den += p[e]; }

  bool sel[NEXP];
#pragma unroll
  for (int e = 0; e < NEXP; e++) sel[e] = false;
  for (int k = 0; k < TOPK; k++) {
    int bj = 0;
    float bv = -1e30f;
#pragma unroll
    for (int e = 0; e < NEXP; e++) {
      if (!sel[e] && s[e] > bv) { bv = s[e]; bj = e; }
    }
    sel[bj] = true;
  }
  float msum = 1e-8f * den;
#pragma unroll
  for (int e = 0; e < NEXP; e++) msum += sel[e] ? p[e] : 0.f;
  const float inv = 1.f / msum;
  if (lane < NEXP) {
    wts[(size_t)token * NEXP + lane] = sel[lane] ? p[lane] * inv : 0.f;
  }
  if (lane == 0) {
#pragma unroll
    for (int e = 0; e < NEXP; e++) {
      if (sel[e]) {
        const int pos = atomicAdd(&cnt[e], 1);
        lists[e * N_TOK + pos] = token;
      }
    }
  }
}

// ---------------------------------------------------------------------------
// Plan: 256-aligned prefix sums of counts -> start rows; flat m-tile table.
// Entry: (expert << 16) | (tile_row0 >> 8)
// ---------------------------------------------------------------------------
__global__ void plan_kernel(const int* __restrict__ cnt, int* __restrict__ start,
                            int* __restrict__ table, int* __restrict__ total) {
  if (threadIdx.x == 0) {
    int r0 = 0, t = 0;
    for (int e = 0; e < NEXP; e++) {
      start[e] = r0;
      const int nt = (cnt[e] + 255) >> 8;
      for (int i = 0; i < nt; i++) table[t++] = (e << 16) | ((r0 >> 8) + i);
      r0 += nt << 8;
    }
    total[0] = t;
  }
}

// ---------------------------------------------------------------------------
// Fill compact-row metadata: rowtok (token index or -1 for pad), roww (weight)
// ---------------------------------------------------------------------------
__global__ __launch_bounds__(256) void fill_kernel(
    const int* __restrict__ cnt, const int* __restrict__ start,
    const int* __restrict__ lists, const float* __restrict__ wts,
    int* __restrict__ rowtok, float* __restrict__ roww) {
  const int e = blockIdx.y;
  const int i = blockIdx.x * 256 + threadIdx.x;
  const int c = cnt[e];
  const int pad = (c + 255) & ~255;
  if (i >= pad) return;
  const int r = start[e] + i;
  if (i < c) {
    const int t = lists[e * N_TOK + i];
    rowtok[r] = t;
    roww[r] = wts[(size_t)t * NEXP + e];
  } else {
    rowtok[r] = -1;
    roww[r] = 0.f;
  }
}

// ---------------------------------------------------------------------------
// fp32 -> f16 elementwise (x)
// ---------------------------------------------------------------------------
__global__ __launch_bounds__(256) void cvt_f32_f16(
    const float* __restrict__ in, f16_t* __restrict__ out, int n4) {
  const int i = blockIdx.x * 256 + threadIdx.x;
  if (i >= n4) return;
  const float4 v = ((const float4*)in)[i];
  f16x4 o;
  o.x = (f16_t)v.x; o.y = (f16_t)v.y; o.z = (f16_t)v.z; o.w = (f16_t)v.w;
  ((f16x4*)out)[i] = o;
}

// ---------------------------------------------------------------------------
// fp32 [E][R][C] -> f16 [E][C][R] tiled transpose-convert (32x32 via LDS)
// ---------------------------------------------------------------------------
__global__ __launch_bounds__(256) void cvt_transpose(
    const float* __restrict__ in, f16_t* __restrict__ out, int R, int C) {
  __shared__ float tile[32][33];
  const int e = blockIdx.z;
  const int r0 = blockIdx.y * 32, c0 = blockIdx.x * 32;
  const int lc = threadIdx.x & 31, lr0 = threadIdx.x >> 5;
  const float* src = in + (size_t)e * R * C;
#pragma unroll
  for (int i = 0; i < 4; i++) {
    const int rr = lr0 + i * 8;
    tile[rr][lc] = src[(size_t)(r0 + rr) * C + c0 + lc];
  }
  __syncthreads();
  f16_t* dst = out + (size_t)e * C * R;
#pragma unroll
  for (int i = 0; i < 4; i++) {
    const int cc = lr0 + i * 8;
    dst[(size_t)(c0 + cc) * R + r0 + lc] = (f16_t)tile[lc][cc];
  }
}

// ===========================================================================
// 256x256 tile, BK=64, 512 threads (8 waves, 2M x 4N), per-wave out 128x64,
// double-buffered LDS (128 KB), ONE __syncthreads per K-tile (2-phase).
// XOR swizzle (both-sides, rule #21): LDS row r's 16B slot s holds global
// k-group s^(r&7). Staged by pre-swizzling the per-lane GLOBAL source
// (gs = (lane&7)^(lane>>3)); ds_read uses kg^(row&7). Spreads each fragment
// read across all 8 slots/32 banks -> minimum LDS cycles (R4's linear layout
// was a 2x conflict: 5.8e7 SQ_LDS_BANK_CONFLICT).
// ===========================================================================

// ---------------------------------------------------------------------------
// Merged sparse GEMM1: hg[r, 0..Hc) = relu( x[rowtok[r]] @ W1[e][:, cH+*] + b1 )
// ---------------------------------------------------------------------------
__global__ __launch_bounds__(512, 2) void gemm1_moe(
    const f16_t* __restrict__ xb, const f16_t* __restrict__ w1t,
    const float* __restrict__ b1, const int* __restrict__ rowtok,
    const int* __restrict__ table, const int* __restrict__ total,
    f16_t* __restrict__ hg, int Hc, int cH, int nbn) {
  int mt, nidx;
  decode_tile(blockIdx.x, nbn, &mt, &nidx);
  if (mt >= total[0]) return;
  const int ent = table[mt];
  const int e = ent >> 16;
  const int r0 = (ent & 0xffff) << 8;
  const int n0 = nidx * 256;  // within chunk

  __shared__ __align__(16) f16_t Asm[2][256 * 64];
  __shared__ __align__(16) f16_t Bsm[2][256 * 64];
  const int tid = threadIdx.x;
  const int wave = tid >> 6, lane = tid & 63;
  const int q = lane >> 4, r = lane & 15;
  const int wr = wave >> 2, wc = wave & 3;       // 2M x 4N wave grid
  const int wrM = wr * 128, wcN = wc * 64;

  const floatx4 zero = {0.f, 0.f, 0.f, 0.f};
  floatx4 acc[8][4];
#pragma unroll
  for (int mi = 0; mi < 8; mi++)
#pragma unroll
    for (int ni = 0; ni < 4; ni++) acc[mi][ni] = zero;

  const f16_t* BT = w1t + (size_t)e * DIM_H * DIM_D + (size_t)cH * DIM_D;

  // staging: 4 rounds x 512 threads x 16B cover 256 rows x 64 k (32 KB) per mat
  // round j, thread: dest row = j*64 + wave*8 + (lane>>3), dest slot = lane&7.
  // Pre-swizzled global k-group: gs = slot ^ (row&7) = (lane&7)^(lane>>3).
  const int gs = (lane & 7) ^ (lane >> 3);
  const f16_t* aptr[4];
  const f16_t* bptr[4];
#pragma unroll
  for (int j = 0; j < 4; j++) {
    const int row = j * 64 + wave * 8 + (lane >> 3);
    const int tok = max(rowtok[r0 + row], 0);
    aptr[j] = xb + (size_t)tok * DIM_D + gs * 8;
    bptr[j] = BT + (size_t)(n0 + row) * DIM_D + gs * 8;
  }
  // LDS dest (wave-uniform base; HW adds lane*16)
#define STAGE1(b, kt)                                               \
  do {                                                              \
    _Pragma("unroll")                                               \
    for (int j = 0; j < 4; j++) {                                   \
      gld_lds16(aptr[j] + (kt) * 64, &Asm[b][j * 4096 + wave * 512]); \
      gld_lds16(bptr[j] + (kt) * 64, &Bsm[b][j * 4096 + wave * 512]); \
    }                                                               \
  } while (0)

  const int rx = r & 7;  // row&7 is identical for every mi/ni fragment row
  const int nk = DIM_D / 64;  // 16 K-tiles
  STAGE1(0, 0);
  int buf = 0;
  for (int t = 0; t < nk; ++t) {
    __syncthreads();  // vmcnt(0): buf's stage landed; prev reads of buf^1 done
    if (t + 1 < nk) STAGE1(buf ^ 1, t + 1);
#pragma unroll
    for (int kk = 0; kk < 2; kk++) {
      const int co = ((kk * 4 + q) ^ rx) << 3;  // swizzled 16B-slot offset
      f16x8 af[8], bf[4];
#pragma unroll
      for (int mi = 0; mi < 8; mi++)
        af[mi] = *(const f16x8*)&Asm[buf][(wrM + mi * 16 + r) * 64 + co];
#pragma unroll
      for (int ni = 0; ni < 4; ni++)
        bf[ni] = *(const f16x8*)&Bsm[buf][(wcN + ni * 16 + r) * 64 + co];
#pragma unroll
      for (int mi = 0; mi < 8; mi++)
#pragma unroll
        for (int ni = 0; ni < 4; ni++)
          acc[mi][ni] = __builtin_amdgcn_mfma_f32_16x16x32_f16(
              af[mi], bf[ni], acc[mi][ni], 0, 0, 0);
    }
    buf ^= 1;
  }
#undef STAGE1

  // D-layout: col = lane&15, row = (lane>>4)*4 + reg
#pragma unroll
  for (int mi = 0; mi < 8; mi++)
#pragma unroll
    for (int ni = 0; ni < 4; ni++) {
      const int gcol = n0 + wcN + ni * 16 + r;
      const float bv = b1[(size_t)e * DIM_H + cH + gcol];
#pragma unroll
      for (int rr = 0; rr < 4; rr++) {
        const int grow = r0 + wrM + mi * 16 + q * 4 + rr;
        hg[(size_t)grow * Hc + gcol] = (f16_t)fmaxf(acc[mi][ni][rr] + bv, 0.f);
      }
    }
}

// ---------------------------------------------------------------------------
// Merged sparse GEMM2: out[rowtok[r]] += roww[r] * ( hg[r] @ W2[e][cH.., :] + b2 )
// Scatter via unsafeAtomicAdd (native global_atomic_add_f32).
// ---------------------------------------------------------------------------
__global__ __launch_bounds__(512, 2) void gemm2_moe(
    const f16_t* __restrict__ hg, const f16_t* __restrict__ w2t,
    const float* __restrict__ b2, const int* __restrict__ rowtok,
    const float* __restrict__ roww, const int* __restrict__ table,
    const int* __restrict__ total, float* __restrict__ out, int Hc, int cH,
    int addBias) {
  int mt, nidx;
  decode_tile(blockIdx.x, DIM_O / 256, &mt, &nidx);
  if (mt >= total[0]) return;
  const int ent = table[mt];
  const int e = ent >> 16;
  const int r0 = (ent & 0xffff) << 8;
  const int n0 = nidx * 256;  // O cols

  __shared__ __align__(16) f16_t Asm[2][256 * 64];
  __shared__ __align__(16) f16_t Bsm[2][256 * 64];
  const int tid = threadIdx.x;
  const int wave = tid >> 6, lane = tid & 63;
  const int q = lane >> 4, r = lane & 15;
  const int wr = wave >> 2, wc = wave & 3;
  const int wrM = wr * 128, wcN = wc * 64;

  const floatx4 zero = {0.f, 0.f, 0.f, 0.f};
  floatx4 acc[8][4];
#pragma unroll
  for (int mi = 0; mi < 8; mi++)
#pragma unroll
    for (int ni = 0; ni < 4; ni++) acc[mi][ni] = zero;

  const f16_t* BT = w2t + (size_t)e * DIM_O * DIM_H + cH;

  const int gs = (lane & 7) ^ (lane >> 3);
  const f16_t* aptr[4];
  const f16_t* bptr[4];
#pragma unroll
  for (int j = 0; j < 4; j++) {
    const int row = j * 64 + wave * 8 + (lane >> 3);
    aptr[j] = hg + (size_t)(r0 + row) * Hc + gs * 8;
    bptr[j] = BT + (size_t)(n0 + row) * DIM_H + gs * 8;
  }
#define STAGE2(b, kt)                                               \
  do {                                                              \
    _Pragma("unroll")                                               \
    for (int j = 0; j < 4; j++) {                                   \
      gld_lds16(aptr[j] + (kt) * 64, &Asm[b][j * 4096 + wave * 512]); \
      gld_lds16(bptr[j] + (kt) * 64, &Bsm[b][j * 4096 + wave * 512]); \
    }                                                               \
  } while (0)

  const int rx = r & 7;
  const int nk = Hc / 64;  // 32 K-tiles at Hc=2048
  STAGE2(0, 0);
  int buf = 0;
  for (int t = 0; t < nk; ++t) {
    __syncthreads();
    if (t + 1 < nk) STAGE2(buf ^ 1, t + 1);
#pragma unroll
    for (int kk = 0; kk < 2; kk++) {
      const int co = ((kk * 4 + q) ^ rx) << 3;
      f16x8 af[8], bf[4];
#pragma unroll
      for (int mi = 0; mi < 8; mi++)
        af[mi] = *(const f16x8*)&Asm[buf][(wrM + mi * 16 + r) * 64 + co];
#pragma unroll
      for (int ni = 0; ni < 4; ni++)
        bf[ni] = *(const f16x8*)&Bsm[buf][(wcN + ni * 16 + r) * 64 + co];
#pragma unroll
      for (int mi = 0; mi < 8; mi++)
#pragma unroll
        for (int ni = 0; ni < 4; ni++)
          acc[mi][ni] = __builtin_amdgcn_mfma_f32_16x16x32_f16(
              af[mi], bf[ni], acc[mi][ni], 0, 0, 0);
    }
    buf ^= 1;
  }
#undef STAGE2

#pragma unroll
  for (int mi = 0; mi < 8; mi++)
#pragma unroll
    for (int ni = 0; ni < 4; ni++) {
      const int gcol = n0 + wcN + ni * 16 + r;
      const float bv = addBias ? b2[(size_t)e * DIM_O + gcol] : 0.f;
#pragma unroll
      for (int rr = 0; rr < 4; rr++) {
        const int grow = r0 + wrM + mi * 16 + q * 4 + rr;
        const int t = rowtok[grow];
        if (t >= 0) {
          const float w = roww[grow];
          unsafeAtomicAdd(&out[(size_t)t * DIM_O + gcol],
                          w * (acc[mi][ni][rr] + bv));
        }
      }
    }
}

// ---------------------------------------------------------------------------
// launch
// ---------------------------------------------------------------------------
extern "C" void kernel_launch(void* const* d_in, const int* in_sizes, int n_in,
                              void* d_out, int out_size, void* d_ws, size_t ws_size,
                              hipStream_t stream) {
  const float* x      = (const float*)d_in[0];
  const float* gate_w = (const float*)d_in[1];
  const float* gate_b = (const float*)d_in[2];
  const float* w1     = (const float*)d_in[3];
  const float* b1     = (const float*)d_in[4];
  const float* w2     = (const float*)d_in[5];
  const float* b2     = (const float*)d_in[6];
  float* out = (float*)d_out;

  // workspace layout
  char* ws = (char*)d_ws;
  const size_t off_wts    = 0;                        // 256 KB
  const size_t off_lists  = off_wts + 262144;         // 256 KB
  const size_t off_cnt    = off_lists + 262144;       // 512 B
  const size_t off_start  = off_cnt + 512;            // 512 B
  const size_t off_total  = off_start + 512;          // 512 B
  const size_t off_table  = off_total + 512;          // 2 KB
  const size_t off_rowtok = off_table + 2048;         // 112 KB (26624*4)
  const size_t off_roww   = off_rowtok + 114688;      // 112 KB
  const size_t META       = 1 << 20;                  // 1 MB reserved
  const size_t off_w1t = META;                                        // 64 MB
  const size_t off_w2t = off_w1t + (size_t)NEXP * DIM_H * DIM_D * 2;  // 64 MB
  const size_t off_xb  = off_w2t + (size_t)NEXP * DIM_O * DIM_H * 2;  // 16 MB
  const size_t off_hg  = off_xb + (size_t)N_TOK * DIM_D * 2;

  float* wts   = (float*)(ws + off_wts);
  int*   lists = (int*)(ws + off_lists);
  int*   cnt   = (int*)(ws + off_cnt);
  int*   start = (int*)(ws + off_start);
  int*   total = (int*)(ws + off_total);
  int*   table = (int*)(ws + off_table);
  int*   rowtok= (int*)(ws + off_rowtok);
  float* roww  = (float*)(ws + off_roww);
  f16_t* w1t   = (f16_t*)(ws + off_w1t);
  f16_t* w2t   = (f16_t*)(ws + off_w2t);
  f16_t* xb    = (f16_t*)(ws + off_xb);
  f16_t* hg    = (f16_t*)(ws + off_hg);

  // pick largest H-chunk that fits (ws_size constant across calls)
  int Hc = 512;
  for (int cand = 4096; cand >= 512; cand >>= 1) {
    if (off_hg + (size_t)CAP_ROWS * cand * 2 <= ws_size) { Hc = cand; break; }
  }
  const int nchunks = DIM_H / Hc;

  hipMemsetAsync(cnt, 0, 512, stream);
  hipMemsetAsync(d_out, 0, (size_t)out_size * sizeof(float), stream);

  gate_kernel<<<N_TOK / 4, 256, 0, stream>>>(x, gate_w, gate_b, wts, lists, cnt);
  plan_kernel<<<1, 64, 0, stream>>>(cnt, start, table, total);
  fill_kernel<<<dim3(N_TOK / 256, NEXP), 256, 0, stream>>>(
      cnt, start, lists, wts, rowtok, roww);

  const int n4 = N_TOK * DIM_D / 4;
  cvt_f32_f16<<<(n4 + 255) / 256, 256, 0, stream>>>(x, xb, n4);
  cvt_transpose<<<dim3(DIM_H / 32, DIM_D / 32, NEXP), 256, 0, stream>>>(
      w1, w1t, DIM_D, DIM_H);
  cvt_transpose<<<dim3(DIM_O / 32, DIM_H / 32, NEXP), 256, 0, stream>>>(
      w2, w2t, DIM_H, DIM_O);

  for (int c = 0; c < nchunks; c++) {
    const int cH = c * Hc;
    const int nbn1 = Hc / 256;
    gemm1_moe<<<dim3(MAX_TILES * nbn1), 512, 0, stream>>>(
        xb, w1t, b1, rowtok, table, total, hg, Hc, cH, nbn1);
    gemm2_moe<<<dim3(MAX_TILES * (DIM_O / 256)), 512, 0, stream>>>(
        hg, w2t, b2, rowtok, roww, table, total, out, Hc, cH, c == 0);
  }
}

// Round 6
// 1359.908 us; speedup vs baseline: 1.1143x; 1.0195x over previous
//
#include <hip/hip_runtime.h>
#include <hip/hip_bf16.h>
#include <hip/hip_fp16.h>

// LieMoE: tokens, in_dim, hidden, out_dim, experts, topk
#define N_TOK 8192
#define DIM_D 1024
#define DIM_H 4096
#define DIM_O 1024
#define NEXP  8
#define TOPK  3

// Sparse routing capacity: sum of per-expert counts == N_TOK*TOPK = 24576.
// 256-aligned per-expert padding adds < 8*256 -> 26624 rows, <= 104 m-tiles.
#define CAP_ROWS  26624
#define MAX_TILES 104
#define NXCD      8
#define NMT_XCD   (MAX_TILES / NXCD)   // 13 m-tiles per XCD chunk

typedef _Float16 f16_t;
typedef _Float16 f16x4 __attribute__((ext_vector_type(4)));
typedef _Float16 f16x8 __attribute__((ext_vector_type(8)));
typedef float    floatx4 __attribute__((ext_vector_type(4)));

__device__ __forceinline__ void gld_lds16(const void* g, void* l) {
  __builtin_amdgcn_global_load_lds(
      (__attribute__((address_space(1))) void*)(void*)g,
      (__attribute__((address_space(3))) void*)l, 16, 0, 0);
}

// T4 counted wait + barrier in ONE asm (order pinned, "memory" stops hoisting).
// N = loads of the NEXT tile that stay in flight ACROSS the barrier.
#define WAITBAR(N) asm volatile("s_waitcnt vmcnt(" #N ")\n\ts_barrier" ::: "memory")
#define BARRIER()  asm volatile("s_barrier" ::: "memory")

// XCD-chunked decode: xcd = bid%8 owns contiguous m-tile chunk (=> ~one
// expert's B panel per XCD L2); within chunk, n varies fastest so consecutive
// blocks on an XCD share the A-tile. (Proven R1 lever: FETCH 957->215 MB.)
__device__ __forceinline__ void decode_tile(int bid, int nbn, int* mt, int* nidx) {
  const int xcd = bid & (NXCD - 1);
  const int lid = bid >> 3;
  const int m_local = lid / nbn;
  *nidx = lid - m_local * nbn;
  *mt = xcd * NMT_XCD + m_local;
}

// ---------------------------------------------------------------------------
// Gate: fp32 scores, softmax, top-3 (stable, first-index wins ties),
// renormalize. Also builds per-expert token lists via atomicAdd.
// One wave per token.
// ---------------------------------------------------------------------------
__global__ __launch_bounds__(256) void gate_kernel(
    const float* __restrict__ x, const float* __restrict__ gw,
    const float* __restrict__ gb, float* __restrict__ wts,
    int* __restrict__ lists, int* __restrict__ cnt) {
  const int token = blockIdx.x * 4 + (threadIdx.x >> 6);
  const int lane = threadIdx.x & 63;
  float s[NEXP];
#pragma unroll
  for (int e = 0; e < NEXP; e++) s[e] = 0.f;
  const float* xr = x + (size_t)token * DIM_D;
  for (int d = lane; d < DIM_D; d += 64) {
    const float xv = xr[d];
    const float* g = gw + (size_t)d * NEXP;
#pragma unroll
    for (int e = 0; e < NEXP; e++) s[e] += xv * g[e];
  }
#pragma unroll
  for (int off = 32; off > 0; off >>= 1) {
#pragma unroll
    for (int e = 0; e < NEXP; e++) s[e] += __shfl_xor(s[e], off, 64);
  }
#pragma unroll
  for (int e = 0; e < NEXP; e++) s[e] += gb[e];

  float mx = s[0];
#pragma unroll
  for (int e = 1; e < NEXP; e++) mx = fmaxf(mx, s[e]);
  float p[NEXP];
  float den = 0.f;
#pragma unroll
  for (int e = 0; e < NEXP; e++) { p[e] = expf(s[e] - mx); den += p[e]; }

  bool sel[NEXP];
#pragma unroll
  for (int e = 0; e < NEXP; e++) sel[e] = false;
  for (int k = 0; k < TOPK; k++) {
    int bj = 0;
    float bv = -1e30f;
#pragma unroll
    for (int e = 0; e < NEXP; e++) {
      if (!sel[e] && s[e] > bv) { bv = s[e]; bj = e; }
    }
    sel[bj] = true;
  }
  float msum = 1e-8f * den;
#pragma unroll
  for (int e = 0; e < NEXP; e++) msum += sel[e] ? p[e] : 0.f;
  const float inv = 1.f / msum;
  if (lane < NEXP) {
    wts[(size_t)token * NEXP + lane] = sel[lane] ? p[lane] * inv : 0.f;
  }
  if (lane == 0) {
#pragma unroll
    for (int e = 0; e < NEXP; e++) {
      if (sel[e]) {
        const int pos = atomicAdd(&cnt[e], 1);
        lists[e * N_TOK + pos] = token;
      }
    }
  }
}

// ---------------------------------------------------------------------------
// Plan: 256-aligned prefix sums of counts -> start rows; flat m-tile table.
// Entry: (expert << 16) | (tile_row0 >> 8)
// ---------------------------------------------------------------------------
__global__ void plan_kernel(const int* __restrict__ cnt, int* __restrict__ start,
                            int* __restrict__ table, int* __restrict__ total) {
  if (threadIdx.x == 0) {
    int r0 = 0, t = 0;
    for (int e = 0; e < NEXP; e++) {
      start[e] = r0;
      const int nt = (cnt[e] + 255) >> 8;
      for (int i = 0; i < nt; i++) table[t++] = (e << 16) | ((r0 >> 8) + i);
      r0 += nt << 8;
    }
    total[0] = t;
  }
}

// ---------------------------------------------------------------------------
// Fill compact-row metadata: rowtok (token index or -1 for pad), roww (weight)
// ---------------------------------------------------------------------------
__global__ __launch_bounds__(256) void fill_kernel(
    const int* __restrict__ cnt, const int* __restrict__ start,
    const int* __restrict__ lists, const float* __restrict__ wts,
    int* __restrict__ rowtok, float* __restrict__ roww) {
  const int e = blockIdx.y;
  const int i = blockIdx.x * 256 + threadIdx.x;
  const int c = cnt[e];
  const int pad = (c + 255) & ~255;
  if (i >= pad) return;
  const int r = start[e] + i;
  if (i < c) {
    const int t = lists[e * N_TOK + i];
    rowtok[r] = t;
    roww[r] = wts[(size_t)t * NEXP + e];
  } else {
    rowtok[r] = -1;
    roww[r] = 0.f;
  }
}

// ---------------------------------------------------------------------------
// fp32 -> f16 elementwise (x)
// ---------------------------------------------------------------------------
__global__ __launch_bounds__(256) void cvt_f32_f16(
    const float* __restrict__ in, f16_t* __restrict__ out, int n4) {
  const int i = blockIdx.x * 256 + threadIdx.x;
  if (i >= n4) return;
  const float4 v = ((const float4*)in)[i];
  f16x4 o;
  o.x = (f16_t)v.x; o.y = (f16_t)v.y; o.z = (f16_t)v.z; o.w = (f16_t)v.w;
  ((f16x4*)out)[i] = o;
}

// ---------------------------------------------------------------------------
// fp32 [E][R][C] -> f16 [E][C][R] tiled transpose-convert (32x32 via LDS)
// ---------------------------------------------------------------------------
__global__ __launch_bounds__(256) void cvt_transpose(
    const float* __restrict__ in, f16_t* __restrict__ out, int R, int C) {
  __shared__ float tile[32][33];
  const int e = blockIdx.z;
  const int r0 = blockIdx.y * 32, c0 = blockIdx.x * 32;
  const int lc = threadIdx.x & 31, lr0 = threadIdx.x >> 5;
  const float* src = in + (size_t)e * R * C;
#pragma unroll
  for (int i = 0; i < 4; i++) {
    const int rr = lr0 + i * 8;
    tile[rr][lc] = src[(size_t)(r0 + rr) * C + c0 + lc];
  }
  __syncthreads();
  f16_t* dst = out + (size_t)e * C * R;
#pragma unroll
  for (int i = 0; i < 4; i++) {
    const int cc = lr0 + i * 8;
    dst[(size_t)(c0 + cc) * R + r0 + lc] = (f16_t)tile[lc][cc];
  }
}

// ===========================================================================
// 256x256 tile, BK=64, 512 threads (8 waves, 2M x 4N), per-wave out 128x64,
// double-buffered LDS (128 KB). XOR swizzle (both-sides, rule #21; R5: bank
// conflicts 5.8e7 -> 0). NEW (T4): counted-vmcnt pipeline — prologue stages
// tiles 0 AND 1; per iter: vmcnt(8)+barrier (next tile's 8 loads stay in
// flight ACROSS the barrier), compute, barrier, STAGE(t+2) into the buffer
// just consumed. Never drains vmcnt to 0 in the main loop, so the 1-block/CU
// schedule (no co-resident block to hide a drain) stops exposing staging
// latency per K-tile. In-loop VMEM = exactly 8 gld_lds per STAGE -> count
// is exact. Overwrite hazard: all waves' ds_reads of buf complete before the
// post-compute barrier (they feed the MFMAs), so STAGE after it is safe.
// ===========================================================================

// ---------------------------------------------------------------------------
// Merged sparse GEMM1: hg[r, 0..Hc) = relu( x[rowtok[r]] @ W1[e][:, cH+*] + b1 )
// ---------------------------------------------------------------------------
__global__ __launch_bounds__(512, 2) void gemm1_moe(
    const f16_t* __restrict__ xb, const f16_t* __restrict__ w1t,
    const float* __restrict__ b1, const int* __restrict__ rowtok,
    const int* __restrict__ table, const int* __restrict__ total,
    f16_t* __restrict__ hg, int Hc, int cH, int nbn) {
  int mt, nidx;
  decode_tile(blockIdx.x, nbn, &mt, &nidx);
  if (mt >= total[0]) return;
  const int ent = table[mt];
  const int e = ent >> 16;
  const int r0 = (ent & 0xffff) << 8;
  const int n0 = nidx * 256;  // within chunk

  __shared__ __align__(16) f16_t Asm[2][256 * 64];
  __shared__ __align__(16) f16_t Bsm[2][256 * 64];
  const int tid = threadIdx.x;
  const int wave = tid >> 6, lane = tid & 63;
  const int q = lane >> 4, r = lane & 15;
  const int wr = wave >> 2, wc = wave & 3;       // 2M x 4N wave grid
  const int wrM = wr * 128, wcN = wc * 64;

  const floatx4 zero = {0.f, 0.f, 0.f, 0.f};
  floatx4 acc[8][4];
#pragma unroll
  for (int mi = 0; mi < 8; mi++)
#pragma unroll
    for (int ni = 0; ni < 4; ni++) acc[mi][ni] = zero;

  const f16_t* BT = w1t + (size_t)e * DIM_H * DIM_D + (size_t)cH * DIM_D;

  // staging: 4 rounds x 512 threads x 16B cover 256 rows x 64 k (32 KB) per mat
  // round j, thread: dest row = j*64 + wave*8 + (lane>>3), dest slot = lane&7.
  // Pre-swizzled global k-group: gs = slot ^ (row&7) = (lane&7)^(lane>>3).
  const int gs = (lane & 7) ^ (lane >> 3);
  const f16_t* aptr[4];
  const f16_t* bptr[4];
#pragma unroll
  for (int j = 0; j < 4; j++) {
    const int row = j * 64 + wave * 8 + (lane >> 3);
    const int tok = max(rowtok[r0 + row], 0);
    aptr[j] = xb + (size_t)tok * DIM_D + gs * 8;
    bptr[j] = BT + (size_t)(n0 + row) * DIM_D + gs * 8;
  }
  // LDS dest (wave-uniform base; HW adds lane*16)
#define STAGE1(b, kt)                                               \
  do {                                                              \
    _Pragma("unroll")                                               \
    for (int j = 0; j < 4; j++) {                                   \
      gld_lds16(aptr[j] + (kt) * 64, &Asm[b][j * 4096 + wave * 512]); \
      gld_lds16(bptr[j] + (kt) * 64, &Bsm[b][j * 4096 + wave * 512]); \
    }                                                               \
  } while (0)

  const int rx = r & 7;  // row&7 is identical for every mi/ni fragment row
  const int nk = DIM_D / 64;  // 16 K-tiles
  STAGE1(0, 0);
  STAGE1(1, 1);
  int buf = 0;
  for (int t = 0; t < nk; ++t) {
    // wait current tile's 8 loads; next tile's 8 stay in flight across barrier
    if (t + 1 < nk) WAITBAR(8); else WAITBAR(0);
#pragma unroll
    for (int kk = 0; kk < 2; kk++) {
      const int co = ((kk * 4 + q) ^ rx) << 3;  // swizzled 16B-slot offset
      f16x8 af[8], bf[4];
#pragma unroll
      for (int mi = 0; mi < 8; mi++)
        af[mi] = *(const f16x8*)&Asm[buf][(wrM + mi * 16 + r) * 64 + co];
#pragma unroll
      for (int ni = 0; ni < 4; ni++)
        bf[ni] = *(const f16x8*)&Bsm[buf][(wcN + ni * 16 + r) * 64 + co];
#pragma unroll
      for (int mi = 0; mi < 8; mi++)
#pragma unroll
        for (int ni = 0; ni < 4; ni++)
          acc[mi][ni] = __builtin_amdgcn_mfma_f32_16x16x32_f16(
              af[mi], bf[ni], acc[mi][ni], 0, 0, 0);
    }
    if (t + 2 < nk) {
      BARRIER();           // all waves done reading buf -> safe to overwrite
      STAGE1(buf, t + 2);  // refill consumed buffer with tile t+2
    }
    buf ^= 1;
  }
#undef STAGE1

  // D-layout: col = lane&15, row = (lane>>4)*4 + reg
#pragma unroll
  for (int mi = 0; mi < 8; mi++)
#pragma unroll
    for (int ni = 0; ni < 4; ni++) {
      const int gcol = n0 + wcN + ni * 16 + r;
      const float bv = b1[(size_t)e * DIM_H + cH + gcol];
#pragma unroll
      for (int rr = 0; rr < 4; rr++) {
        const int grow = r0 + wrM + mi * 16 + q * 4 + rr;
        hg[(size_t)grow * Hc + gcol] = (f16_t)fmaxf(acc[mi][ni][rr] + bv, 0.f);
      }
    }
}

// ---------------------------------------------------------------------------
// Merged sparse GEMM2: out[rowtok[r]] += roww[r] * ( hg[r] @ W2[e][cH.., :] + b2 )
// Scatter via unsafeAtomicAdd (native global_atomic_add_f32).
// ---------------------------------------------------------------------------
__global__ __launch_bounds__(512, 2) void gemm2_moe(
    const f16_t* __restrict__ hg, const f16_t* __restrict__ w2t,
    const float* __restrict__ b2, const int* __restrict__ rowtok,
    const float* __restrict__ roww, const int* __restrict__ table,
    const int* __restrict__ total, float* __restrict__ out, int Hc, int cH,
    int addBias) {
  int mt, nidx;
  decode_tile(blockIdx.x, DIM_O / 256, &mt, &nidx);
  if (mt >= total[0]) return;
  const int ent = table[mt];
  const int e = ent >> 16;
  const int r0 = (ent & 0xffff) << 8;
  const int n0 = nidx * 256;  // O cols

  __shared__ __align__(16) f16_t Asm[2][256 * 64];
  __shared__ __align__(16) f16_t Bsm[2][256 * 64];
  const int tid = threadIdx.x;
  const int wave = tid >> 6, lane = tid & 63;
  const int q = lane >> 4, r = lane & 15;
  const int wr = wave >> 2, wc = wave & 3;
  const int wrM = wr * 128, wcN = wc * 64;

  const floatx4 zero = {0.f, 0.f, 0.f, 0.f};
  floatx4 acc[8][4];
#pragma unroll
  for (int mi = 0; mi < 8; mi++)
#pragma unroll
    for (int ni = 0; ni < 4; ni++) acc[mi][ni] = zero;

  const f16_t* BT = w2t + (size_t)e * DIM_O * DIM_H + cH;

  const int gs = (lane & 7) ^ (lane >> 3);
  const f16_t* aptr[4];
  const f16_t* bptr[4];
#pragma unroll
  for (int j = 0; j < 4; j++) {
    const int row = j * 64 + wave * 8 + (lane >> 3);
    aptr[j] = hg + (size_t)(r0 + row) * Hc + gs * 8;
    bptr[j] = BT + (size_t)(n0 + row) * DIM_H + gs * 8;
  }
#define STAGE2(b, kt)                                               \
  do {                                                              \
    _Pragma("unroll")                                               \
    for (int j = 0; j < 4; j++) {                                   \
      gld_lds16(aptr[j] + (kt) * 64, &Asm[b][j * 4096 + wave * 512]); \
      gld_lds16(bptr[j] + (kt) * 64, &Bsm[b][j * 4096 + wave * 512]); \
    }                                                               \
  } while (0)

  const int rx = r & 7;
  const int nk = Hc / 64;  // 32 K-tiles at Hc=2048
  STAGE2(0, 0);
  STAGE2(1, 1);
  int buf = 0;
  for (int t = 0; t < nk; ++t) {
    if (t + 1 < nk) WAITBAR(8); else WAITBAR(0);
#pragma unroll
    for (int kk = 0; kk < 2; kk++) {
      const int co = ((kk * 4 + q) ^ rx) << 3;
      f16x8 af[8], bf[4];
#pragma unroll
      for (int mi = 0; mi < 8; mi++)
        af[mi] = *(const f16x8*)&Asm[buf][(wrM + mi * 16 + r) * 64 + co];
#pragma unroll
      for (int ni = 0; ni < 4; ni++)
        bf[ni] = *(const f16x8*)&Bsm[buf][(wcN + ni * 16 + r) * 64 + co];
#pragma unroll
      for (int mi = 0; mi < 8; mi++)
#pragma unroll
        for (int ni = 0; ni < 4; ni++)
          acc[mi][ni] = __builtin_amdgcn_mfma_f32_16x16x32_f16(
              af[mi], bf[ni], acc[mi][ni], 0, 0, 0);
    }
    if (t + 2 < nk) {
      BARRIER();
      STAGE2(buf, t + 2);
    }
    buf ^= 1;
  }
#undef STAGE2

#pragma unroll
  for (int mi = 0; mi < 8; mi++)
#pragma unroll
    for (int ni = 0; ni < 4; ni++) {
      const int gcol = n0 + wcN + ni * 16 + r;
      const float bv = addBias ? b2[(size_t)e * DIM_O + gcol] : 0.f;
#pragma unroll
      for (int rr = 0; rr < 4; rr++) {
        const int grow = r0 + wrM + mi * 16 + q * 4 + rr;
        const int t = rowtok[grow];
        if (t >= 0) {
          const float w = roww[grow];
          unsafeAtomicAdd(&out[(size_t)t * DIM_O + gcol],
                          w * (acc[mi][ni][rr] + bv));
        }
      }
    }
}

// ---------------------------------------------------------------------------
// launch
// ---------------------------------------------------------------------------
extern "C" void kernel_launch(void* const* d_in, const int* in_sizes, int n_in,
                              void* d_out, int out_size, void* d_ws, size_t ws_size,
                              hipStream_t stream) {
  const float* x      = (const float*)d_in[0];
  const float* gate_w = (const float*)d_in[1];
  const float* gate_b = (const float*)d_in[2];
  const float* w1     = (const float*)d_in[3];
  const float* b1     = (const float*)d_in[4];
  const float* w2     = (const float*)d_in[5];
  const float* b2     = (const float*)d_in[6];
  float* out = (float*)d_out;

  // workspace layout
  char* ws = (char*)d_ws;
  const size_t off_wts    = 0;                        // 256 KB
  const size_t off_lists  = off_wts + 262144;         // 256 KB
  const size_t off_cnt    = off_lists + 262144;       // 512 B
  const size_t off_start  = off_cnt + 512;            // 512 B
  const size_t off_total  = off_start + 512;          // 512 B
  const size_t off_table  = off_total + 512;          // 2 KB
  const size_t off_rowtok = off_table + 2048;         // 112 KB (26624*4)
  const size_t off_roww   = off_rowtok + 114688;      // 112 KB
  const size_t META       = 1 << 20;                  // 1 MB reserved
  const size_t off_w1t = META;                                        // 64 MB
  const size_t off_w2t = off_w1t + (size_t)NEXP * DIM_H * DIM_D * 2;  // 64 MB
  const size_t off_xb  = off_w2t + (size_t)NEXP * DIM_O * DIM_H * 2;  // 16 MB
  const size_t off_hg  = off_xb + (size_t)N_TOK * DIM_D * 2;

  float* wts   = (float*)(ws + off_wts);
  int*   lists = (int*)(ws + off_lists);
  int*   cnt   = (int*)(ws + off_cnt);
  int*   start = (int*)(ws + off_start);
  int*   total = (int*)(ws + off_total);
  int*   table = (int*)(ws + off_table);
  int*   rowtok= (int*)(ws + off_rowtok);
  float* roww  = (float*)(ws + off_roww);
  f16_t* w1t   = (f16_t*)(ws + off_w1t);
  f16_t* w2t   = (f16_t*)(ws + off_w2t);
  f16_t* xb    = (f16_t*)(ws + off_xb);
  f16_t* hg    = (f16_t*)(ws + off_hg);

  // pick largest H-chunk that fits (ws_size constant across calls)
  int Hc = 512;
  for (int cand = 4096; cand >= 512; cand >>= 1) {
    if (off_hg + (size_t)CAP_ROWS * cand * 2 <= ws_size) { Hc = cand; break; }
  }
  const int nchunks = DIM_H / Hc;

  hipMemsetAsync(cnt, 0, 512, stream);
  hipMemsetAsync(d_out, 0, (size_t)out_size * sizeof(float), stream);

  gate_kernel<<<N_TOK / 4, 256, 0, stream>>>(x, gate_w, gate_b, wts, lists, cnt);
  plan_kernel<<<1, 64, 0, stream>>>(cnt, start, table, total);
  fill_kernel<<<dim3(N_TOK / 256, NEXP), 256, 0, stream>>>(
      cnt, start, lists, wts, rowtok, roww);

  const int n4 = N_TOK * DIM_D / 4;
  cvt_f32_f16<<<(n4 + 255) / 256, 256, 0, stream>>>(x, xb, n4);
  cvt_transpose<<<dim3(DIM_H / 32, DIM_D / 32, NEXP), 256, 0, stream>>>(
      w1, w1t, DIM_D, DIM_H);
  cvt_transpose<<<dim3(DIM_O / 32, DIM_H / 32, NEXP), 256, 0, stream>>>(
      w2, w2t, DIM_H, DIM_O);

  for (int c = 0; c < nchunks; c++) {
    const int cH = c * Hc;
    const int nbn1 = Hc / 256;
    gemm1_moe<<<dim3(MAX_TILES * nbn1), 512, 0, stream>>>(
        xb, w1t, b1, rowtok, table, total, hg, Hc, cH, nbn1);
    gemm2_moe<<<dim3(MAX_TILES * (DIM_O / 256)), 512, 0, stream>>>(
        hg, w2t, b2, rowtok, roww, table, total, out, Hc, cH, c == 0);
  }
}

// Round 7
// 1170.493 us; speedup vs baseline: 1.2946x; 1.1618x over previous
//
#include <hip/hip_runtime.h>
#include <hip/hip_bf16.h>
#include <hip/hip_fp16.h>

// LieMoE: tokens, in_dim, hidden, out_dim, experts, topk
#define N_TOK 8192
#define DIM_D 1024
#define DIM_H 4096
#define DIM_O 1024
#define NEXP  8
#define TOPK  3

// Sparse routing capacity: sum of per-expert counts == N_TOK*TOPK = 24576.
// 128-aligned per-expert padding adds < 8*128 -> 25600 rows, <= 200 m-tiles.
#define CAP_ROWS  25600
#define MAX_TILES 200
#define NXCD      8
#define MT_PER    (MAX_TILES / NXCD)   // 25 m-tiles per XCD chunk
#define MT_GRP    5                    // m-tiles per supertile group (divides MT_PER)

typedef _Float16 f16_t;
typedef _Float16 f16x4 __attribute__((ext_vector_type(4)));
typedef _Float16 f16x8 __attribute__((ext_vector_type(8)));
typedef float    floatx4 __attribute__((ext_vector_type(4)));

__device__ __forceinline__ void gld_lds16(const void* g, void* l) {
  __builtin_amdgcn_global_load_lds(
      (__attribute__((address_space(1))) void*)(void*)g,
      (__attribute__((address_space(3))) void*)l, 16, 0, 0);
}

// XCD-chunked supertile decode (proven R1 lever: FETCH 957->215 MB).
__device__ __forceinline__ void decode_tile(int bid, int nbn, int* mt, int* nidx) {
  const int xcd = bid & (NXCD - 1);
  const int lid = bid >> 3;                 // 0 .. MT_PER*nbn - 1
  const int per = MT_GRP * nbn;             // blocks per group
  const int group = lid / per;              // 0 .. MT_PER/MT_GRP - 1
  const int rem = lid - group * per;
  const int n = rem / MT_GRP;
  const int g = rem - n * MT_GRP;
  *mt = xcd * MT_PER + group * MT_GRP + g;
  *nidx = n;
}

// ---------------------------------------------------------------------------
// Gate: fp32 scores, softmax, top-3 (stable, first-index wins ties),
// renormalize. Builds per-expert token lists; packs the token's selection
// slot k (0..2) into bits [15:14] of the list entry (token < 2^13).
// ---------------------------------------------------------------------------
__global__ __launch_bounds__(256) void gate_kernel(
    const float* __restrict__ x, const float* __restrict__ gw,
    const float* __restrict__ gb, float* __restrict__ wts,
    int* __restrict__ lists, int* __restrict__ cnt) {
  const int token = blockIdx.x * 4 + (threadIdx.x >> 6);
  const int lane = threadIdx.x & 63;
  float s[NEXP];
#pragma unroll
  for (int e = 0; e < NEXP; e++) s[e] = 0.f;
  const float* xr = x + (size_t)token * DIM_D;
  for (int d = lane; d < DIM_D; d += 64) {
    const float xv = xr[d];
    const float* g = gw + (size_t)d * NEXP;
#pragma unroll
    for (int e = 0; e < NEXP; e++) s[e] += xv * g[e];
  }
#pragma unroll
  for (int off = 32; off > 0; off >>= 1) {
#pragma unroll
    for (int e = 0; e < NEXP; e++) s[e] += __shfl_xor(s[e], off, 64);
  }
#pragma unroll
  for (int e = 0; e < NEXP; e++) s[e] += gb[e];

  float mx = s[0];
#pragma unroll
  for (int e = 1; e < NEXP; e++) mx = fmaxf(mx, s[e]);
  float p[NEXP];
  float den = 0.f;
#pragma unroll
  for (int e = 0; e < NEXP; e++) { p[e] = expf(s[e] - mx); den += p[e]; }

  bool sel[NEXP];
#pragma unroll
  for (int e = 0; e < NEXP; e++) sel[e] = false;
  for (int k = 0; k < TOPK; k++) {
    int bj = 0;
    float bv = -1e30f;
#pragma unroll
    for (int e = 0; e < NEXP; e++) {
      if (!sel[e] && s[e] > bv) { bv = s[e]; bj = e; }
    }
    sel[bj] = true;
  }
  float msum = 1e-8f * den;
#pragma unroll
  for (int e = 0; e < NEXP; e++) msum += sel[e] ? p[e] : 0.f;
  const float inv = 1.f / msum;
  if (lane < NEXP) {
    wts[(size_t)token * NEXP + lane] = sel[lane] ? p[lane] * inv : 0.f;
  }
  if (lane == 0) {
    int kk = 0;
#pragma unroll
    for (int e = 0; e < NEXP; e++) {
      if (sel[e]) {
        const int pos = atomicAdd(&cnt[e], 1);
        lists[e * N_TOK + pos] = token | (kk << 14);
        kk++;
      }
    }
  }
}

// ---------------------------------------------------------------------------
// Plan: aligned prefix sums of counts -> start rows; flat m-tile table.
// Entry: (expert << 16) | (tile_row0 >> 7)
// ---------------------------------------------------------------------------
__global__ void plan_kernel(const int* __restrict__ cnt, int* __restrict__ start,
                            int* __restrict__ table, int* __restrict__ total) {
  if (threadIdx.x == 0) {
    int r0 = 0, t = 0;
    for (int e = 0; e < NEXP; e++) {
      start[e] = r0;
      const int nt = (cnt[e] + 127) >> 7;
      for (int i = 0; i < nt; i++) table[t++] = (e << 16) | ((r0 >> 7) + i);
      r0 += nt << 7;
    }
    total[0] = t;
  }
}

// ---------------------------------------------------------------------------
// Fill compact-row metadata: rowtok (token index or -1 for pad), roww (weight),
// and the inverse map tok2row[t][k] = compact row of the token's k-th expert.
// ---------------------------------------------------------------------------
__global__ __launch_bounds__(256) void fill_kernel(
    const int* __restrict__ cnt, const int* __restrict__ start,
    const int* __restrict__ lists, const float* __restrict__ wts,
    int* __restrict__ rowtok, float* __restrict__ roww,
    int* __restrict__ tok2row) {
  const int e = blockIdx.y;
  const int i = blockIdx.x * 256 + threadIdx.x;
  const int c = cnt[e];
  const int pad = (c + 127) & ~127;
  if (i >= pad) return;
  const int r = start[e] + i;
  if (i < c) {
    const int v = lists[e * N_TOK + i];
    const int t = v & 0x3FFF;
    const int k = v >> 14;
    rowtok[r] = t;
    roww[r] = wts[(size_t)t * NEXP + e];
    tok2row[t * 4 + k] = r;
  } else {
    rowtok[r] = -1;
    roww[r] = 0.f;
  }
}

// ---------------------------------------------------------------------------
// fp32 -> f16 elementwise (x)
// ---------------------------------------------------------------------------
__global__ __launch_bounds__(256) void cvt_f32_f16(
    const float* __restrict__ in, f16_t* __restrict__ out, int n4) {
  const int i = blockIdx.x * 256 + threadIdx.x;
  if (i >= n4) return;
  const float4 v = ((const float4*)in)[i];
  f16x4 o;
  o.x = (f16_t)v.x; o.y = (f16_t)v.y; o.z = (f16_t)v.z; o.w = (f16_t)v.w;
  ((f16x4*)out)[i] = o;
}

// ---------------------------------------------------------------------------
// fp32 [E][R][C] -> f16 [E][C][R] tiled transpose-convert (32x32 via LDS)
// ---------------------------------------------------------------------------
__global__ __launch_bounds__(256) void cvt_transpose(
    const float* __restrict__ in, f16_t* __restrict__ out, int R, int C) {
  __shared__ float tile[32][33];
  const int e = blockIdx.z;
  const int r0 = blockIdx.y * 32, c0 = blockIdx.x * 32;
  const int lc = threadIdx.x & 31, lr0 = threadIdx.x >> 5;
  const float* src = in + (size_t)e * R * C;
#pragma unroll
  for (int i = 0; i < 4; i++) {
    const int rr = lr0 + i * 8;
    tile[rr][lc] = src[(size_t)(r0 + rr) * C + c0 + lc];
  }
  __syncthreads();
  f16_t* dst = out + (size_t)e * C * R;
#pragma unroll
  for (int i = 0; i < 4; i++) {
    const int cc = lr0 + i * 8;
    dst[(size_t)(c0 + cc) * R + r0 + lc] = (f16_t)tile[lc][cc];
  }
}

// ---------------------------------------------------------------------------
// Merged sparse GEMM1: hg[r, 0..Hc) = relu( x[rowtok[r]] @ W1[e][:, cH+*] + b1 )
// Proven R1 structure: 128x128, BK=32, 4 waves, single-buffer 2-barrier,
// global_load_lds + XOR-swizzled source k-groups.
// ---------------------------------------------------------------------------
__global__ __launch_bounds__(256, 2) void gemm1_moe(
    const f16_t* __restrict__ xb, const f16_t* __restrict__ w1t,
    const float* __restrict__ b1, const int* __restrict__ rowtok,
    const int* __restrict__ table, const int* __restrict__ total,
    f16_t* __restrict__ hg, int Hc, int cH, int nbn) {
  int mt, nidx;
  decode_tile(blockIdx.x, nbn, &mt, &nidx);
  if (mt >= total[0]) return;
  const int ent = table[mt];
  const int e = ent >> 16;
  const int r0 = (ent & 0xffff) << 7;
  const int n0 = nidx * 128;  // within chunk

  __shared__ __align__(16) f16_t Asm[128 * 32];
  __shared__ __align__(16) f16_t Bsm[128 * 32];
  const int tid = threadIdx.x;
  const int wave = tid >> 6, lane = tid & 63;
  const int q = lane >> 4, r = lane & 15;
  const int waveM = (wave >> 1) * 64, waveN = (wave & 1) * 64;

  const floatx4 zero = {0.f, 0.f, 0.f, 0.f};
  floatx4 acc[4][4];
#pragma unroll
  for (int mi = 0; mi < 4; mi++)
#pragma unroll
    for (int ni = 0; ni < 4; ni++) acc[mi][ni] = zero;

  const f16_t* BT = w1t + (size_t)e * DIM_H * DIM_D + (size_t)cH * DIM_D;

  const int s0 = tid, s1 = tid + 256;
  const int row0 = s0 >> 2, row1 = s1 >> 2;
  const int gs0 = (s0 & 3) ^ ((row0 >> 1) & 3);
  const int gs1 = (s1 & 3) ^ ((row1 >> 1) & 3);
  const int tok0 = max(rowtok[r0 + row0], 0);
  const int tok1 = max(rowtok[r0 + row1], 0);
  const f16_t* Ar0 = xb + (size_t)tok0 * DIM_D + gs0 * 8;
  const f16_t* Ar1 = xb + (size_t)tok1 * DIM_D + gs1 * 8;
  const f16_t* Br0 = BT + (size_t)(n0 + row0) * DIM_D + gs0 * 8;
  const f16_t* Br1 = BT + (size_t)(n0 + row1) * DIM_D + gs1 * 8;
  f16_t* AsmB0 = &Asm[(wave * 64) * 8];
  f16_t* AsmB1 = &Asm[(256 + wave * 64) * 8];
  f16_t* BsmB0 = &Bsm[(wave * 64) * 8];
  f16_t* BsmB1 = &Bsm[(256 + wave * 64) * 8];

  for (int k0 = 0; k0 < DIM_D; k0 += 32) {
    gld_lds16(Ar0 + k0, AsmB0);
    gld_lds16(Ar1 + k0, AsmB1);
    gld_lds16(Br0 + k0, BsmB0);
    gld_lds16(Br1 + k0, BsmB1);
    __syncthreads();
    f16x8 af[4], bfr[4];
#pragma unroll
    for (int i = 0; i < 4; i++) {
      const int rowa = waveM + i * 16 + r;
      af[i] = *(const f16x8*)&Asm[rowa * 32 + ((q ^ ((rowa >> 1) & 3)) << 3)];
      const int rowb = waveN + i * 16 + r;
      bfr[i] = *(const f16x8*)&Bsm[rowb * 32 + ((q ^ ((rowb >> 1) & 3)) << 3)];
    }
#pragma unroll
    for (int mi = 0; mi < 4; mi++)
#pragma unroll
      for (int ni = 0; ni < 4; ni++)
        acc[mi][ni] = __builtin_amdgcn_mfma_f32_16x16x32_f16(
            af[mi], bfr[ni], acc[mi][ni], 0, 0, 0);
    __syncthreads();
  }

  // D-layout: col = lane&15, row = (lane>>4)*4 + reg
#pragma unroll
  for (int mi = 0; mi < 4; mi++)
#pragma unroll
    for (int ni = 0; ni < 4; ni++) {
      const int gcol = n0 + waveN + ni * 16 + r;
      const float bv = b1[(size_t)e * DIM_H + cH + gcol];
#pragma unroll
      for (int rr = 0; rr < 4; rr++) {
        const int grow = r0 + waveM + mi * 16 + q * 4 + rr;
        hg[(size_t)grow * Hc + gcol] = (f16_t)fmaxf(acc[mi][ni][rr] + bv, 0.f);
      }
    }
}

// ---------------------------------------------------------------------------
// Merged sparse GEMM2: og[r, :] = hg[r] @ W2[e][cH.., :] (+ b2 on chunk 0)
// NO ATOMICS: plain f16 stores to the per-compact-row partial buffer og.
// (R3 measured the 25M-atomic scatter at ~84 us/dispatch; combine_kernel
// now does the weighted 3-row sum with unique ownership instead.)
// ---------------------------------------------------------------------------
__global__ __launch_bounds__(256, 2) void gemm2_moe(
    const f16_t* __restrict__ hg, const f16_t* __restrict__ w2t,
    const float* __restrict__ b2, const int* __restrict__ table,
    const int* __restrict__ total, f16_t* __restrict__ og, int Hc, int cH,
    int addBias) {
  int mt, nidx;
  decode_tile(blockIdx.x, DIM_O / 128, &mt, &nidx);
  if (mt >= total[0]) return;
  const int ent = table[mt];
  const int e = ent >> 16;
  const int r0 = (ent & 0xffff) << 7;
  const int n0 = nidx * 128;  // O cols

  __shared__ __align__(16) f16_t Asm[128 * 32];
  __shared__ __align__(16) f16_t Bsm[128 * 32];
  const int tid = threadIdx.x;
  const int wave = tid >> 6, lane = tid & 63;
  const int q = lane >> 4, r = lane & 15;
  const int waveM = (wave >> 1) * 64, waveN = (wave & 1) * 64;

  const floatx4 zero = {0.f, 0.f, 0.f, 0.f};
  floatx4 acc[4][4];
#pragma unroll
  for (int mi = 0; mi < 4; mi++)
#pragma unroll
    for (int ni = 0; ni < 4; ni++) acc[mi][ni] = zero;

  const f16_t* BT = w2t + (size_t)e * DIM_O * DIM_H + cH;

  const int s0 = tid, s1 = tid + 256;
  const int row0 = s0 >> 2, row1 = s1 >> 2;
  const int gs0 = (s0 & 3) ^ ((row0 >> 1) & 3);
  const int gs1 = (s1 & 3) ^ ((row1 >> 1) & 3);
  const f16_t* Ar0 = hg + (size_t)(r0 + row0) * Hc + gs0 * 8;
  const f16_t* Ar1 = hg + (size_t)(r0 + row1) * Hc + gs1 * 8;
  const f16_t* Br0 = BT + (size_t)(n0 + row0) * DIM_H + gs0 * 8;
  const f16_t* Br1 = BT + (size_t)(n0 + row1) * DIM_H + gs1 * 8;
  f16_t* AsmB0 = &Asm[(wave * 64) * 8];
  f16_t* AsmB1 = &Asm[(256 + wave * 64) * 8];
  f16_t* BsmB0 = &Bsm[(wave * 64) * 8];
  f16_t* BsmB1 = &Bsm[(256 + wave * 64) * 8];

  for (int k0 = 0; k0 < Hc; k0 += 32) {
    gld_lds16(Ar0 + k0, AsmB0);
    gld_lds16(Ar1 + k0, AsmB1);
    gld_lds16(Br0 + k0, BsmB0);
    gld_lds16(Br1 + k0, BsmB1);
    __syncthreads();
    f16x8 af[4], bfr[4];
#pragma unroll
    for (int i = 0; i < 4; i++) {
      const int rowa = waveM + i * 16 + r;
      af[i] = *(const f16x8*)&Asm[rowa * 32 + ((q ^ ((rowa >> 1) & 3)) << 3)];
      const int rowb = waveN + i * 16 + r;
      bfr[i] = *(const f16x8*)&Bsm[rowb * 32 + ((q ^ ((rowb >> 1) & 3)) << 3)];
    }
#pragma unroll
    for (int mi = 0; mi < 4; mi++)
#pragma unroll
      for (int ni = 0; ni < 4; ni++)
        acc[mi][ni] = __builtin_amdgcn_mfma_f32_16x16x32_f16(
            af[mi], bfr[ni], acc[mi][ni], 0, 0, 0);
    __syncthreads();
  }

#pragma unroll
  for (int mi = 0; mi < 4; mi++)
#pragma unroll
    for (int ni = 0; ni < 4; ni++) {
      const int gcol = n0 + waveN + ni * 16 + r;
      const float bv = addBias ? b2[(size_t)e * DIM_O + gcol] : 0.f;
#pragma unroll
      for (int rr = 0; rr < 4; rr++) {
        const int grow = r0 + waveM + mi * 16 + q * 4 + rr;
        og[(size_t)grow * DIM_O + gcol] = (f16_t)(acc[mi][ni][rr] + bv);
      }
    }
}

// ---------------------------------------------------------------------------
// Combine: out[t, :] (+)= sum_k roww[r_k] * og[r_k, :]  — unique owner per
// (t, col), plain f32 stores (no atomics). first=1 overwrites (replaces the
// out memset); later chunks accumulate in f32 (no precision risk).
// ---------------------------------------------------------------------------
__global__ __launch_bounds__(256) void combine_kernel(
    const f16_t* __restrict__ og, const float* __restrict__ roww,
    const int* __restrict__ tok2row, float* __restrict__ out, int first) {
  const int t = blockIdx.x;
  const int c0 = threadIdx.x * 4;
  const int ra = tok2row[t * 4 + 0];
  const int rb = tok2row[t * 4 + 1];
  const int rc = tok2row[t * 4 + 2];
  const float wa = roww[ra], wb = roww[rb], wc = roww[rc];
  const f16x4 a = *(const f16x4*)&og[(size_t)ra * DIM_O + c0];
  const f16x4 b = *(const f16x4*)&og[(size_t)rb * DIM_O + c0];
  const f16x4 c = *(const f16x4*)&og[(size_t)rc * DIM_O + c0];
  float4 o;
  o.x = wa * (float)a.x + wb * (float)b.x + wc * (float)c.x;
  o.y = wa * (float)a.y + wb * (float)b.y + wc * (float)c.y;
  o.z = wa * (float)a.z + wb * (float)b.z + wc * (float)c.z;
  o.w = wa * (float)a.w + wb * (float)b.w + wc * (float)c.w;
  float4* op = (float4*)&out[(size_t)t * DIM_O + c0];
  if (!first) {
    const float4 p = *op;
    o.x += p.x; o.y += p.y; o.z += p.z; o.w += p.w;
  }
  *op = o;
}

// ---------------------------------------------------------------------------
// launch
// ---------------------------------------------------------------------------
extern "C" void kernel_launch(void* const* d_in, const int* in_sizes, int n_in,
                              void* d_out, int out_size, void* d_ws, size_t ws_size,
                              hipStream_t stream) {
  const float* x      = (const float*)d_in[0];
  const float* gate_w = (const float*)d_in[1];
  const float* gate_b = (const float*)d_in[2];
  const float* w1     = (const float*)d_in[3];
  const float* b1     = (const float*)d_in[4];
  const float* w2     = (const float*)d_in[5];
  const float* b2     = (const float*)d_in[6];
  float* out = (float*)d_out;

  // workspace layout
  char* ws = (char*)d_ws;
  const size_t off_wts     = 0;                        // 256 KB
  const size_t off_lists   = off_wts + 262144;         // 256 KB
  const size_t off_cnt     = off_lists + 262144;       // 512 B
  const size_t off_start   = off_cnt + 512;            // 512 B
  const size_t off_total   = off_start + 512;          // 512 B
  const size_t off_table   = off_total + 512;          // 2 KB
  const size_t off_rowtok  = off_table + 2048;         // 100 KB
  const size_t off_roww    = off_rowtok + 102400;      // 100 KB
  const size_t off_tok2row = off_roww + 102400;        // 128 KB (8192*4*4)
  const size_t META        = 1 << 20;                  // 1 MB reserved
  const size_t off_w1t = META;                                        // 64 MB
  const size_t off_w2t = off_w1t + (size_t)NEXP * DIM_H * DIM_D * 2;  // 64 MB
  const size_t off_xb  = off_w2t + (size_t)NEXP * DIM_O * DIM_H * 2;  // 16 MB
  const size_t off_hg  = off_xb + (size_t)N_TOK * DIM_D * 2;
  const size_t og_sz   = (size_t)CAP_ROWS * DIM_O * 2;                // 52.4 MB

  float* wts    = (float*)(ws + off_wts);
  int*   lists  = (int*)(ws + off_lists);
  int*   cnt    = (int*)(ws + off_cnt);
  int*   start  = (int*)(ws + off_start);
  int*   total  = (int*)(ws + off_total);
  int*   table  = (int*)(ws + off_table);
  int*   rowtok = (int*)(ws + off_rowtok);
  float* roww   = (float*)(ws + off_roww);
  int*   tok2row= (int*)(ws + off_tok2row);
  f16_t* w1t    = (f16_t*)(ws + off_w1t);
  f16_t* w2t    = (f16_t*)(ws + off_w2t);
  f16_t* xb     = (f16_t*)(ws + off_xb);
  f16_t* hg     = (f16_t*)(ws + off_hg);

  // pick largest H-chunk such that hg + og fit (ws_size constant across calls)
  int Hc = 512;
  for (int cand = 4096; cand >= 512; cand >>= 1) {
    if (off_hg + (size_t)CAP_ROWS * cand * 2 + og_sz <= ws_size) { Hc = cand; break; }
  }
  const int nchunks = DIM_H / Hc;
  f16_t* og = (f16_t*)(ws + off_hg + (size_t)CAP_ROWS * Hc * 2);

  hipMemsetAsync(cnt, 0, 512, stream);

  gate_kernel<<<N_TOK / 4, 256, 0, stream>>>(x, gate_w, gate_b, wts, lists, cnt);
  plan_kernel<<<1, 64, 0, stream>>>(cnt, start, table, total);
  fill_kernel<<<dim3(N_TOK / 256, NEXP), 256, 0, stream>>>(
      cnt, start, lists, wts, rowtok, roww, tok2row);

  const int n4 = N_TOK * DIM_D / 4;
  cvt_f32_f16<<<(n4 + 255) / 256, 256, 0, stream>>>(x, xb, n4);
  cvt_transpose<<<dim3(DIM_H / 32, DIM_D / 32, NEXP), 256, 0, stream>>>(
      w1, w1t, DIM_D, DIM_H);
  cvt_transpose<<<dim3(DIM_O / 32, DIM_H / 32, NEXP), 256, 0, stream>>>(
      w2, w2t, DIM_H, DIM_O);

  for (int c = 0; c < nchunks; c++) {
    const int cH = c * Hc;
    const int nbn1 = Hc / 128;
    gemm1_moe<<<dim3(nbn1 * MAX_TILES), 256, 0, stream>>>(
        xb, w1t, b1, rowtok, table, total, hg, Hc, cH, nbn1);
    gemm2_moe<<<dim3((DIM_O / 128) * MAX_TILES), 256, 0, stream>>>(
        hg, w2t, b2, table, total, og, Hc, cH, c == 0);
    combine_kernel<<<N_TOK, 256, 0, stream>>>(og, roww, tok2row, out, c == 0);
  }
}